// Round 2
// baseline (95.539 us; speedup 1.0000x reference)
//
#include <hip/hip_runtime.h>
#include <math.h>

#define NC 5
#define EPS_F 0.1f

// Fast reciprocal: v_rcp_f32 (~1 ulp), avoids the 12-instruction precise-div
// sequence that dominated the round-1 critical path.
__device__ __forceinline__ float frcp(float v) { return __builtin_amdgcn_rcpf(v); }

// One thread handles TWO rows (i and i+half) for ILP: two independent
// Newton chains interleave in the scheduler. q = x·Wᵀ + b; solve
// KL(softmax(t·log q) || uniform) = eps for t in (0,1], t=1 if feasible.
// f(t) = t·E_p[u] - log Z(t) + log n - eps, f'(t) = t·Var_p(u), u = s - max s.
__global__ __launch_bounds__(256) void klproj_kernel(
    const float* __restrict__ x,
    const float* __restrict__ W,
    const float* __restrict__ b,
    float* __restrict__ out,
    int half)
{
    int i = blockIdx.x * blockDim.x + threadIdx.x;
    if (i >= half) return;

    const float C = 1.6094379124341003f - EPS_F;   // log(5) - eps

    float u[2][NC], u2[2][NC], t[2], lo[2], hi[2], f1[2];

    // --- per-row setup: q, s = log q, u = s - max, u2 = u^2 ---
#pragma unroll
    for (int r = 0; r < 2; ++r) {
        int row = i + r * half;
        float xv[NC];
#pragma unroll
        for (int k = 0; k < NC; ++k) xv[k] = x[row * NC + k];
        float s[NC];
        float m = -1e30f;
#pragma unroll
        for (int j = 0; j < NC; ++j) {
            float q = b[j];
#pragma unroll
            for (int k = 0; k < NC; ++k) q = fmaf(xv[k], W[j * NC + k], q);
            s[j] = __logf(q);
            m = fmaxf(m, s[j]);
        }
#pragma unroll
        for (int j = 0; j < NC; ++j) {
            u[r][j]  = s[j] - m;
            u2[r][j] = u[r][j] * u[r][j];
        }
    }

    // f, f' at a given t (all divides via v_rcp)
    auto eval = [&](int r, float tt, float& f, float& fp) {
        float Z = 0.f, T1 = 0.f, T2 = 0.f;
#pragma unroll
        for (int j = 0; j < NC; ++j) {
            float ej = __expf(tt * u[r][j]);
            Z += ej;
            T1 = fmaf(ej, u[r][j], T1);
            T2 = fmaf(ej, u2[r][j], T2);
        }
        float rZ = frcp(Z);
        float Eu = T1 * rZ;
        f  = fmaf(tt, Eu, C - __logf(Z));
        fp = tt * fmaf(-Eu, Eu, T2 * rZ);
    };

    // --- feasibility at t=1 + smart init t0 = sqrt(eps/KL1) (KL ~ KL1·t²) ---
    bool any = false;
#pragma unroll
    for (int r = 0; r < 2; ++r) {
        float fp1;
        eval(r, 1.0f, f1[r], fp1);
        lo[r] = 0.f; hi[r] = 1.f;
        float kl1 = f1[r] + EPS_F;                  // = KL(p(1)||u) >= 0
        float t0  = 0.316227766017f * __frsqrt_rn(kl1);  // sqrt(eps/KL1)
        t[r] = (t0 > 0.f && t0 < 1.f) ? t0 : 0.5f;  // NaN/inf-safe guard
        any = any || (f1[r] > 0.f);
    }

    // --- bracketed Newton, 6 iterations (skipped by fully-feasible waves) ---
    if (any) {
#pragma unroll
        for (int it = 0; it < 6; ++it) {
#pragma unroll
            for (int r = 0; r < 2; ++r) {
                float f, fp;
                eval(r, t[r], f, fp);
                bool pos = f > 0.f;
                hi[r] = pos ? t[r] : hi[r];
                lo[r] = pos ? lo[r] : t[r];
                float tn = t[r] - f * frcp(fp);
                t[r] = (tn > lo[r] && tn < hi[r]) ? tn : 0.5f * (lo[r] + hi[r]);
            }
        }
    }

    // --- final p = softmax(t·u); exact t=1 for feasible rows ---
#pragma unroll
    for (int r = 0; r < 2; ++r) {
        float tf = (f1[r] > 0.f) ? t[r] : 1.0f;
        float e[NC], Z = 0.f;
#pragma unroll
        for (int j = 0; j < NC; ++j) { e[j] = __expf(tf * u[r][j]); Z += e[j]; }
        float rZ = frcp(Z);
        int row = i + r * half;
#pragma unroll
        for (int j = 0; j < NC; ++j) out[row * NC + j] = e[j] * rZ;
    }
}

extern "C" void kernel_launch(void* const* d_in, const int* in_sizes, int n_in,
                              void* d_out, int out_size, void* d_ws, size_t ws_size,
                              hipStream_t stream) {
    const float* x = (const float*)d_in[0];
    const float* W = (const float*)d_in[1];
    const float* b = (const float*)d_in[2];
    float* out = (float*)d_out;
    int batch = in_sizes[0] / NC;
    int half = batch / 2;

    int block = 256;
    int grid = (half + block - 1) / block;
    klproj_kernel<<<grid, block, 0, stream>>>(x, W, b, out, half);
}